// Round 3
// baseline (202.221 us; speedup 1.0000x reference)
//
#include <hip/hip_runtime.h>

#define NB    8192
#define NEI   64
#define DIM   128
#define D2    256
#define NR_W  1001   // 2*CNT_R+1
#define NR_Z  1000   // 2*CNT_R
#define EPB_LD 136   // bf16 elems per LDS row (128 + 8 pad)
#define BPB   4      // b's per block

typedef __attribute__((ext_vector_type(8))) short bf16x8;   // 8 bf16 = 4 VGPR
typedef __attribute__((ext_vector_type(4))) float f32x4;

__device__ __forceinline__ ushort f2bf(float x) {
    union { float f; unsigned u; } c; c.f = x;
    unsigned u = c.u;
    return (ushort)((u + 0x7fffu + ((u >> 16) & 1u)) >> 16);   // RNE
}

// ---------------- precompute kernels ----------------

__global__ void k_norm(const float* __restrict__ w_r_table, float* __restrict__ norm_t) {
    int r = blockIdx.x;          // 0..1000
    int t = threadIdx.x;         // 0..127
    float v = w_r_table[r * DIM + t];
    float s = v * v;
    #pragma unroll
    for (int m = 1; m < 64; m <<= 1) s += __shfl_xor(s, m);
    __shared__ float sh[2];
    if ((t & 63) == 0) sh[t >> 6] = s;
    __syncthreads();
    float tot = sh[0] + sh[1];
    norm_t[r * DIM + t] = v / sqrtf(tot);
}

// Tq[r][o] = attn_W_b[o] + sum_{k<128} attn_W_w[o][k] * zq_table[r][k]
__global__ void k_tq(const float* __restrict__ zq_table, const float* __restrict__ W,
                     const float* __restrict__ bias, float* __restrict__ tq_t) {
    int r = blockIdx.x;          // 0..999
    int o = threadIdx.x;         // 0..255
    __shared__ float4 z4[32];
    if (o < 32) z4[o] = ((const float4*)(zq_table + r * DIM))[o];
    __syncthreads();
    const float4* wr = (const float4*)(W + o * D2);
    float acc = bias[o];
    #pragma unroll 8
    for (int i = 0; i < 32; ++i) {
        float4 wv = wr[i], zv = z4[i];
        acc += wv.x*zv.x + wv.y*zv.y + wv.z*zv.z + wv.w*zv.w;
    }
    tq_t[r * D2 + o] = acc;
}

// B fragments in mfma_16x16x32_bf16 order (same layout as verified round 2):
// bfrag[((nt*4+kt)*64 + lane)*8 + j] = W2[k][o], o = nt*16+(lane&15), k = kt*32+(lane>>4)*8+j
__global__ void k_bfrag(const float* __restrict__ W, ushort* __restrict__ bfrag) {
    int nt = blockIdx.x;         // 0..15
    int kt = blockIdx.y;         // 0..3
    int l  = threadIdx.x;        // 0..63
    int o  = nt * 16 + (l & 15);
    int k  = kt * 32 + (l >> 4) * 8;
    const float4* src = (const float4*)(W + o * D2 + DIM + k);
    float4 a = src[0], c = src[1];
    uint4 w;
    w.x = f2bf(a.x) | ((unsigned)f2bf(a.y) << 16);
    w.y = f2bf(a.z) | ((unsigned)f2bf(a.w) << 16);
    w.z = f2bf(c.x) | ((unsigned)f2bf(c.y) << 16);
    w.w = f2bf(c.z) | ((unsigned)f2bf(c.w) << 16);
    *(uint4*)(bfrag + ((nt * 4 + kt) * 64 + l) * 8) = w;
}

// ---------------- main fused kernel: BPB b's per block, prefetch pipeline ----

__global__ __launch_bounds__(256, 3) void k_main(
    const float* __restrict__ e_emb,    // (B,64,128)
    const float* __restrict__ rw,       // (B,64)
    const int*   __restrict__ nei_rid,  // (B,64)
    const int*   __restrict__ q_rid,    // (B,)
    const float* __restrict__ norm_t,   // (1001,128)
    const float* __restrict__ tq_t,     // (1000,256)
    const ushort* __restrict__ bfrag,   // (16,4,64,8) bf16
    const float* __restrict__ u_a_w,    // (256,)
    float* __restrict__ out)            // (B,64)
{
    __shared__ ushort ep16[NEI * EPB_LD];   // 17408 B
    __shared__ float  alpw[4][NEI];         // 1024 B
    __shared__ int    rids_s[BPB * NEI];    // 1024 B

    const int b0 = blockIdx.x * BPB;
    const int t = threadIdx.x;
    const int wave = t >> 6, lane = t & 63;
    const int ln = lane & 15, hi = lane >> 4;
    const int row = t >> 2, q = t & 3;

    // ---- prologue: per-block-constant state ----
    int my_rid = nei_rid[b0 * NEI + t];          // rids for all BPB b's (64 each)

    int qrs[BPB];
    #pragma unroll
    for (int i = 0; i < BPB; ++i) qrs[i] = q_rid[b0 + i];   // uniform loads

    float ua4[4];
    #pragma unroll
    for (int nt = 0; nt < 4; ++nt) ua4[nt] = u_a_w[wave * 64 + nt * 16 + ln];

    bf16x8 bfr_[4][4];                           // this wave's 16 B-fragments, held all block
    #pragma unroll
    for (int nt = 0; nt < 4; ++nt)
        #pragma unroll
        for (int kt = 0; kt < 4; ++kt)
            bfr_[nt][kt] = *(const bf16x8*)(bfrag + (((wave*4 + nt)*4 + kt)*64 + lane)*8);

    rids_s[t] = my_rid;

    // ---- prefetch slot 0 (b = b0) ----
    float4 ev[2][8];
    float  tq4p[2][4];
    float  rwp[2];
    {
        const float4* esrc = (const float4*)(e_emb + ((size_t)b0 * NEI + row) * DIM + q * 32);
        #pragma unroll
        for (int k = 0; k < 8; ++k) ev[0][k] = esrc[k];
        #pragma unroll
        for (int nt = 0; nt < 4; ++nt) tq4p[0][nt] = tq_t[qrs[0] * D2 + wave*64 + nt*16 + ln];
        rwp[0] = rw[(size_t)b0 * NEI + (t & 63)];
    }

    __syncthreads();    // rids_s visible

    #pragma unroll
    for (int i = 0; i < BPB; ++i) {
        const int cur = i & 1, nxt = cur ^ 1;

        // ---- projection (4 lanes/row), norm fetched on demand (L2-hot) ----
        {
            const int rid = rids_s[i * NEI + row];
            const float4* nsrc = (const float4*)(norm_t + rid * DIM + q * 32);
            float4 nv[8];
            #pragma unroll
            for (int k = 0; k < 8; ++k) nv[k] = nsrc[k];
            float part = 0.f;
            #pragma unroll
            for (int k = 0; k < 8; ++k) {
                float4 e4 = ev[cur][k];
                part += e4.x*nv[k].x + e4.y*nv[k].y + e4.z*nv[k].z + e4.w*nv[k].w;
            }
            part += __shfl_xor(part, 1);
            part += __shfl_xor(part, 2);
            const float d = part;               // full-row e . n
            ushort* dst = &ep16[row * EPB_LD + q * 32];
            #pragma unroll
            for (int g = 0; g < 4; ++g) {
                float4 lo = ev[cur][g*2], hi4 = ev[cur][g*2+1];
                float4 nl = nv[g*2],     nh  = nv[g*2+1];
                lo.x = fmaf(-d, nl.x, lo.x); lo.y = fmaf(-d, nl.y, lo.y);
                lo.z = fmaf(-d, nl.z, lo.z); lo.w = fmaf(-d, nl.w, lo.w);
                hi4.x = fmaf(-d, nh.x, hi4.x); hi4.y = fmaf(-d, nh.y, hi4.y);
                hi4.z = fmaf(-d, nh.z, hi4.z); hi4.w = fmaf(-d, nh.w, hi4.w);
                uint4 w;
                w.x = f2bf(lo.x)  | ((unsigned)f2bf(lo.y)  << 16);
                w.y = f2bf(lo.z)  | ((unsigned)f2bf(lo.w)  << 16);
                w.z = f2bf(hi4.x) | ((unsigned)f2bf(hi4.y) << 16);
                w.w = f2bf(hi4.z) | ((unsigned)f2bf(hi4.w) << 16);
                *(uint4*)(dst + g * 8) = w;
            }
        }

        // ---- issue prefetch for b0+i+1 (covered by MFMA+epilogue below) ----
        if (i + 1 < BPB) {
            const float4* esrc = (const float4*)(e_emb + ((size_t)(b0+i+1) * NEI + row) * DIM + q * 32);
            #pragma unroll
            for (int k = 0; k < 8; ++k) ev[nxt][k] = esrc[k];
            #pragma unroll
            for (int nt = 0; nt < 4; ++nt) tq4p[nxt][nt] = tq_t[qrs[i+1] * D2 + wave*64 + nt*16 + ln];
            rwp[nxt] = rw[(size_t)(b0+i+1) * NEI + (t & 63)];
        }

        __syncthreads();

        // ---- MFMA + fused epilogue (tanh + u_a dot), per M-tile ----
        #pragma unroll
        for (int mt = 0; mt < 4; ++mt) {
            bf16x8 a_[4];
            #pragma unroll
            for (int kt = 0; kt < 4; ++kt)
                a_[kt] = *(const bf16x8*)&ep16[(mt*16 + ln) * EPB_LD + kt*32 + hi*8];
            f32x4 acc[4];
            #pragma unroll
            for (int nt = 0; nt < 4; ++nt) acc[nt] = (f32x4){0.f, 0.f, 0.f, 0.f};
            #pragma unroll
            for (int kt = 0; kt < 4; ++kt)
                #pragma unroll
                for (int nt = 0; nt < 4; ++nt)
                    acc[nt] = __builtin_amdgcn_mfma_f32_16x16x32_bf16(a_[kt], bfr_[nt][kt], acc[nt], 0, 0, 0);
            // C/D layout: col = lane&15, row = mt*16 + (lane>>4)*4 + j
            float pr[4] = {0.f, 0.f, 0.f, 0.f};
            #pragma unroll
            for (int nt = 0; nt < 4; ++nt)
                #pragma unroll
                for (int j = 0; j < 4; ++j) {
                    float v = acc[nt][j] + tq4p[cur][nt];
                    float e2 = __expf(2.f * v);                       // v_exp
                    float r  = __builtin_amdgcn_rcpf(e2 + 1.f);       // v_rcp, no IEEE div
                    float h  = fmaf(-2.f, r, 1.f);                    // tanh(v)
                    pr[j] += ua4[nt] * h;
                }
            #pragma unroll
            for (int m = 1; m < 16; m <<= 1)
                #pragma unroll
                for (int j = 0; j < 4; ++j) pr[j] += __shfl_xor(pr[j], m);
            if (ln == 0) {
                #pragma unroll
                for (int j = 0; j < 4; ++j) alpw[wave][mt*16 + hi*4 + j] = pr[j];
            }
        }
        __syncthreads();

        // ---- softmax over 64 neighbors + rw (shift-invariant; logits bounded ~9) ----
        if (t < NEI) {
            float a = alpw[0][t] + alpw[1][t] + alpw[2][t] + alpw[3][t];
            float p = __expf(a);
            float s = p;
            #pragma unroll
            for (int m = 1; m < 64; m <<= 1) s += __shfl_xor(s, m);
            out[(size_t)(b0 + i) * NEI + t] = fmaf(p, __builtin_amdgcn_rcpf(s), rwp[cur]);
        }
        // next iteration's proj writes ep16 only after this loop's barrier-protected reads
    }
}

// ---------------- launch ----------------

extern "C" void kernel_launch(void* const* d_in, const int* in_sizes, int n_in,
                              void* d_out, int out_size, void* d_ws, size_t ws_size,
                              hipStream_t stream) {
    const float* e_emb   = (const float*)d_in[0];
    const float* rw      = (const float*)d_in[1];
    const float* w_r_tab = (const float*)d_in[2];
    const float* zq_tab  = (const float*)d_in[3];
    const float* attn_W  = (const float*)d_in[4];
    const float* attn_b  = (const float*)d_in[5];
    const float* u_a_w   = (const float*)d_in[6];
    // d_in[7] = u_a_b: cancels in softmax, unused
    const int*   nei_rid = (const int*)d_in[8];
    const int*   q_rid   = (const int*)d_in[9];
    float* out = (float*)d_out;

    float* ws = (float*)d_ws;
    float* norm_t = ws;                             // 1001*128 f32
    float* tq_t   = norm_t + NR_W * DIM;            // 1000*256 f32
    ushort* bfrag = (ushort*)(tq_t + NR_Z * D2);    // 16*4*64*8 bf16

    k_norm<<<NR_W, DIM, 0, stream>>>(w_r_tab, norm_t);
    k_tq<<<NR_Z, D2, 0, stream>>>(zq_tab, attn_W, attn_b, tq_t);
    k_bfrag<<<dim3(16, 4), 64, 0, stream>>>(attn_W, bfrag);
    k_main<<<NB / BPB, 256, 0, stream>>>(e_emb, rw, nei_rid, q_rid,
                                         norm_t, tq_t, bfrag, u_a_w, out);
}

// Round 4
// 126.879 us; speedup vs baseline: 1.5938x; 1.5938x over previous
//
#include <hip/hip_runtime.h>

#define NB    8192
#define NEI   64
#define DIM   128
#define D2    256
#define NR_W  1001   // 2*CNT_R+1
#define NR_Z  1000   // 2*CNT_R
#define EPB_LD 136   // bf16 elems per LDS row (128 + 8 pad)

typedef __attribute__((ext_vector_type(8))) short bf16x8;   // 8 bf16 = 4 VGPR
typedef __attribute__((ext_vector_type(4))) float f32x4;

__device__ __forceinline__ ushort f2bf(float x) {
    union { float f; unsigned u; } c; c.f = x;
    unsigned u = c.u;
    return (ushort)((u + 0x7fffu + ((u >> 16) & 1u)) >> 16);   // RNE
}

// ---------------- precompute kernels ----------------

__global__ void k_norm(const float* __restrict__ w_r_table, float* __restrict__ norm_t) {
    int r = blockIdx.x;          // 0..1000
    int t = threadIdx.x;         // 0..127
    float v = w_r_table[r * DIM + t];
    float s = v * v;
    #pragma unroll
    for (int m = 1; m < 64; m <<= 1) s += __shfl_xor(s, m);
    __shared__ float sh[2];
    if ((t & 63) == 0) sh[t >> 6] = s;
    __syncthreads();
    float tot = sh[0] + sh[1];
    norm_t[r * DIM + t] = v / sqrtf(tot);
}

// Tq[r][o] = attn_W_b[o] + sum_{k<128} attn_W_w[o][k] * zq_table[r][k]
__global__ void k_tq(const float* __restrict__ zq_table, const float* __restrict__ W,
                     const float* __restrict__ bias, float* __restrict__ tq_t) {
    int r = blockIdx.x;          // 0..999
    int o = threadIdx.x;         // 0..255
    __shared__ float4 z4[32];
    if (o < 32) z4[o] = ((const float4*)(zq_table + r * DIM))[o];
    __syncthreads();
    const float4* wr = (const float4*)(W + o * D2);
    float acc = bias[o];
    #pragma unroll 8
    for (int i = 0; i < 32; ++i) {
        float4 wv = wr[i], zv = z4[i];
        acc += wv.x*zv.x + wv.y*zv.y + wv.z*zv.z + wv.w*zv.w;
    }
    tq_t[r * D2 + o] = acc;
}

// B fragments in mfma_16x16x32_bf16 order (layout verified in round 2):
// bfrag[((nt*4+kt)*64 + lane)*8 + j] = W2[k][o], o = nt*16+(lane&15), k = kt*32+(lane>>4)*8+j
__global__ void k_bfrag(const float* __restrict__ W, ushort* __restrict__ bfrag) {
    int nt = blockIdx.x;         // 0..15
    int kt = blockIdx.y;         // 0..3
    int l  = threadIdx.x;        // 0..63
    int o  = nt * 16 + (l & 15);
    int k  = kt * 32 + (l >> 4) * 8;
    const float4* src = (const float4*)(W + o * D2 + DIM + k);
    float4 a = src[0], c = src[1];
    uint4 w;
    w.x = f2bf(a.x) | ((unsigned)f2bf(a.y) << 16);
    w.y = f2bf(a.z) | ((unsigned)f2bf(a.w) << 16);
    w.z = f2bf(c.x) | ((unsigned)f2bf(c.y) << 16);
    w.w = f2bf(c.z) | ((unsigned)f2bf(c.w) << 16);
    *(uint4*)(bfrag + ((nt * 4 + kt) * 64 + l) * 8) = w;
}

// ---------------- main fused kernel: one block per b ----------------
// __launch_bounds__(256, 2): 256-VGPR budget so the 64-VGPR B-fragment set
// stays RESIDENT. Round-2's 80-VGPR allocation forced the compiler to
// rematerialize bfrag loads inside the mt-loop (VALU bloat, MfmaUtil 8.5%);
// round-3's (256,3) + reg double-buffer spilled (WRITE_SIZE 94 MB).

__global__ __launch_bounds__(256, 2) void k_main(
    const float* __restrict__ e_emb,    // (B,64,128)
    const float* __restrict__ rw,       // (B,64)
    const int*   __restrict__ nei_rid,  // (B,64)
    const int*   __restrict__ q_rid,    // (B,)
    const float* __restrict__ norm_t,   // (1001,128)
    const float* __restrict__ tq_t,     // (1000,256)
    const ushort* __restrict__ bfrag,   // (16,4,64,8) bf16
    const float* __restrict__ u_a_w,    // (256,)
    float* __restrict__ out)            // (B,64)
{
    __shared__ ushort ep16[NEI * EPB_LD];   // 17408 B
    __shared__ float  alpw[4][NEI];         // 1024 B

    const int b = blockIdx.x;
    const int t = threadIdx.x;
    const int wave = t >> 6, lane = t & 63;
    const int ln = lane & 15, hi = lane >> 4;

    // ---- load e rows (4 lanes/row), project in registers, convert to bf16 LDS ----
    {
        const int row = t >> 2, q = t & 3;
        const float4* esrc = (const float4*)(e_emb + ((size_t)b * NEI + row) * DIM + q * 32);
        const int rid = nei_rid[b * NEI + row];
        const float4* nsrc = (const float4*)(norm_t + rid * DIM + q * 32);
        float4 ev[8], nv[8];
        #pragma unroll
        for (int i = 0; i < 8; ++i) { ev[i] = esrc[i]; nv[i] = nsrc[i]; }
        float part = 0.f;
        #pragma unroll
        for (int i = 0; i < 8; ++i)
            part += ev[i].x*nv[i].x + ev[i].y*nv[i].y + ev[i].z*nv[i].z + ev[i].w*nv[i].w;
        part += __shfl_xor(part, 1);
        part += __shfl_xor(part, 2);
        const float d = part;               // full-row e . n
        ushort* dst = &ep16[row * EPB_LD + q * 32];
        #pragma unroll
        for (int g = 0; g < 4; ++g) {
            float4 lo = ev[g*2], hi4 = ev[g*2+1];
            float4 nl = nv[g*2], nh  = nv[g*2+1];
            lo.x = fmaf(-d, nl.x, lo.x); lo.y = fmaf(-d, nl.y, lo.y);
            lo.z = fmaf(-d, nl.z, lo.z); lo.w = fmaf(-d, nl.w, lo.w);
            hi4.x = fmaf(-d, nh.x, hi4.x); hi4.y = fmaf(-d, nh.y, hi4.y);
            hi4.z = fmaf(-d, nh.z, hi4.z); hi4.w = fmaf(-d, nh.w, hi4.w);
            uint4 w;
            w.x = f2bf(lo.x)  | ((unsigned)f2bf(lo.y)  << 16);
            w.y = f2bf(lo.z)  | ((unsigned)f2bf(lo.w)  << 16);
            w.z = f2bf(hi4.x) | ((unsigned)f2bf(hi4.y) << 16);
            w.w = f2bf(hi4.z) | ((unsigned)f2bf(hi4.w) << 16);
            *(uint4*)(dst + g * 8) = w;
        }
    }

    // per-lane epilogue constants: o = wave*64 + nt*16 + (lane&15)
    const int qr = q_rid[b];
    float tq4[4], ua4[4];
    #pragma unroll
    for (int nt = 0; nt < 4; ++nt) {
        int o = wave * 64 + nt * 16 + ln;
        tq4[nt] = tq_t[qr * D2 + o];
        ua4[nt] = u_a_w[o];
    }

    // B fragments for this wave's 64 output cols: 16 x bf16x8, resident in VGPRs
    bf16x8 bfr_[4][4];
    #pragma unroll
    for (int nt = 0; nt < 4; ++nt)
        #pragma unroll
        for (int kt = 0; kt < 4; ++kt)
            bfr_[nt][kt] = *(const bf16x8*)(bfrag + (((wave*4 + nt)*4 + kt)*64 + lane)*8);

    __syncthreads();

    // GEMM (waves split N) + fused epilogue per M-tile
    #pragma unroll
    for (int mt = 0; mt < 4; ++mt) {
        bf16x8 a_[4];
        #pragma unroll
        for (int kt = 0; kt < 4; ++kt)
            a_[kt] = *(const bf16x8*)&ep16[(mt*16 + ln) * EPB_LD + kt*32 + hi*8];
        f32x4 acc[4];
        #pragma unroll
        for (int nt = 0; nt < 4; ++nt) acc[nt] = (f32x4){0.f, 0.f, 0.f, 0.f};
        #pragma unroll
        for (int kt = 0; kt < 4; ++kt)
            #pragma unroll
            for (int nt = 0; nt < 4; ++nt)
                acc[nt] = __builtin_amdgcn_mfma_f32_16x16x32_bf16(a_[kt], bfr_[nt][kt], acc[nt], 0, 0, 0);
        // C/D layout: col = lane&15, row = mt*16 + (lane>>4)*4 + j
        float pr[4] = {0.f, 0.f, 0.f, 0.f};
        #pragma unroll
        for (int nt = 0; nt < 4; ++nt)
            #pragma unroll
            for (int j = 0; j < 4; ++j) {
                float v = acc[nt][j] + tq4[nt];
                float e2 = __expf(2.f * v);                       // v_exp
                float r  = __builtin_amdgcn_rcpf(e2 + 1.f);       // v_rcp, no IEEE div
                float h  = fmaf(-2.f, r, 1.f);                    // tanh(v)
                pr[j] += ua4[nt] * h;
            }
        #pragma unroll
        for (int m = 1; m < 16; m <<= 1)                          // xor 1/2/4/8 -> DPP
            #pragma unroll
            for (int j = 0; j < 4; ++j) pr[j] += __shfl_xor(pr[j], m);
        if (ln == 0) {
            #pragma unroll
            for (int j = 0; j < 4; ++j) alpw[wave][mt*16 + hi*4 + j] = pr[j];
        }
    }
    __syncthreads();

    // softmax over 64 neighbors + rw (shift-invariant; logits bounded by sum|u_a| ~ 9)
    if (t < NEI) {
        float a = alpw[0][t] + alpw[1][t] + alpw[2][t] + alpw[3][t];
        float p = __expf(a);
        float s = p;
        #pragma unroll
        for (int m = 1; m < 64; m <<= 1) s += __shfl_xor(s, m);
        out[(size_t)b * NEI + t] = fmaf(p, __builtin_amdgcn_rcpf(s), rw[(size_t)b * NEI + t]);
    }
}

// ---------------- launch ----------------

extern "C" void kernel_launch(void* const* d_in, const int* in_sizes, int n_in,
                              void* d_out, int out_size, void* d_ws, size_t ws_size,
                              hipStream_t stream) {
    const float* e_emb   = (const float*)d_in[0];
    const float* rw      = (const float*)d_in[1];
    const float* w_r_tab = (const float*)d_in[2];
    const float* zq_tab  = (const float*)d_in[3];
    const float* attn_W  = (const float*)d_in[4];
    const float* attn_b  = (const float*)d_in[5];
    const float* u_a_w   = (const float*)d_in[6];
    // d_in[7] = u_a_b: cancels in softmax, unused
    const int*   nei_rid = (const int*)d_in[8];
    const int*   q_rid   = (const int*)d_in[9];
    float* out = (float*)d_out;

    float* ws = (float*)d_ws;
    float* norm_t = ws;                             // 1001*128 f32
    float* tq_t   = norm_t + NR_W * DIM;            // 1000*256 f32
    ushort* bfrag = (ushort*)(tq_t + NR_Z * D2);    // 16*4*64*8 bf16

    k_norm<<<NR_W, DIM, 0, stream>>>(w_r_tab, norm_t);
    k_tq<<<NR_Z, D2, 0, stream>>>(zq_tab, attn_W, attn_b, tq_t);
    k_bfrag<<<dim3(16, 4), 64, 0, stream>>>(attn_W, bfrag);
    k_main<<<NB, 256, 0, stream>>>(e_emb, rw, nei_rid, q_rid,
                                   norm_t, tq_t, bfrag, u_a_w, out);
}